// Round 1
// baseline (321.119 us; speedup 1.0000x reference)
//
#include <hip/hip_runtime.h>
#include <stdint.h>

// Bloom filter, 2^27 bits, 7 hashes = 7 CONSECUTIVE bits starting at
//   p = ((uint32)v * 2654435761u) & (2^27 - 1)   (wraps mod 2^27)
// Harness dtypes: integer inputs -> int32; bool output -> int32 (0/1).
//
// R9: replaced the two-pass bucket scatter (A+B, ~145us combined) with a
// direct fire-and-forget global atomicOr insert. The bits state is a pure
// OR-reduction (commutative/associative/idempotent) -> deterministic final
// state regardless of atomic order; no spill/cap machinery. H is rebuilt in
// a separate fully-coalesced pass (16MiB read, 4MiB write) which also warms
// L3 with the bits array for the query.
// Query fix: bits gathers were __builtin_nontemporal_load -> explicitly
// uncached -> every gather paid a full HBM line fetch (FETCH_SIZE 133MB vs
// ~52MB unique). Now plain cached loads; nontemporal kept only for the
// streaming input/output.

#define NUM_BITS_LOG2 27
#define NUM_BITS (1u << NUM_BITS_LOG2)
#define BIT_MASK (NUM_BITS - 1u)
#define NUM_WORDS (NUM_BITS >> 6)             // 2^21 u64 words = 16 MiB
#define WORD_MASK (NUM_WORDS - 1u)
#define PRIME 2654435761u
#define H_WORDS (NUM_WORDS >> 2)              // 2^19 u64 H-words = 4 MiB

typedef int vint4 __attribute__((ext_vector_type(4)));
typedef unsigned long long vull2 __attribute__((ext_vector_type(2)));

// ---------------- workspace layout (bytes) ----------------
// [0, 16777216)            bits   u64 x 2^21   (16 MiB)
// [16777216, 20971520)     H      u64 x 2^19   (4 MiB)
#define WS_REQUIRED 20971520ull

// ---------- zero the fine bitmap (streaming stores) ----------
__global__ __launch_bounds__(256) void zero_bits_kernel(vull2* __restrict__ bits, int n2) {
    int i = blockIdx.x * 256 + threadIdx.x;
    if (i < n2) { vull2 z = {0ull, 0ull}; __builtin_nontemporal_store(z, &bits[i]); }
}

// ---------- insert: fire-and-forget device-scope atomicOr ----------
__device__ __forceinline__ void insert_one_atomic(uint32_t v,
                                                  unsigned long long* __restrict__ bits) {
    uint32_t p = (v * PRIME) & BIT_MASK;
    uint32_t w = p >> 6, s = p & 63u;
    atomicOr(bits + w, 0x7Full << s);
    if (s > 57u) atomicOr(bits + ((w + 1u) & WORD_MASK), 0x7Full >> (64u - s));
}

__global__ __launch_bounds__(256) void insert_atomic_kernel(const int* __restrict__ vals, int n,
                                                            unsigned long long* __restrict__ bits) {
    int t = blockIdx.x * 256 + threadIdx.x;
    int base = t * 4;
    if (base + 3 < n) {
        vint4 v = __builtin_nontemporal_load((const vint4*)vals + t);
        insert_one_atomic((uint32_t)v.x, bits);
        insert_one_atomic((uint32_t)v.y, bits);
        insert_one_atomic((uint32_t)v.z, bits);
        insert_one_atomic((uint32_t)v.w, bits);
    } else {
        for (int j = base; j < n; ++j) insert_one_atomic((uint32_t)vals[j], bits);
    }
}

// ---------- H build: coalesced bits -> nibble-AND summary ----------
// 16 nibble-AND bits of one u64 fine word, compacted to low 16 bits
__device__ __forceinline__ unsigned long long nib16(unsigned long long a) {
    unsigned long long t = a & (a >> 1);
    unsigned long long u = t & (t >> 2);                // bit 4k = AND of bits 4k..4k+3
    u &= 0x1111111111111111ull;
    u |= u >> 3;  u &= 0x0303030303030303ull;
    u |= u >> 6;  u &= 0x000F000F000F000Full;
    u |= u >> 12; u &= 0x000000FF000000FFull;
    u |= u >> 24; return u & 0xFFFFull;
}

__global__ __launch_bounds__(256) void build_h_kernel(
    const unsigned long long* __restrict__ bits, unsigned long long* __restrict__ H)
{
    uint32_t i = blockIdx.x * 256 + threadIdx.x;        // [0, 2^19), grid exact
    const vull2* b2 = (const vull2*)bits + (size_t)i * 2;
    vull2 a = b2[0];                                    // temporal: warms L2/L3 with bits
    vull2 b = b2[1];
    unsigned long long hw = nib16(a[0])
                          | (nib16(a[1]) << 16)
                          | (nib16(b[0]) << 32)
                          | (nib16(b[1]) << 48);
    H[i] = hw;                                          // temporal: H wants to live in L2
}

// ---------- query: H pre-filter (L2-resident), fine bitmap only on pass ----------
__device__ __forceinline__ int query_one_branchy(uint32_t v,
                                                 const unsigned long long* __restrict__ bits) {
    uint32_t p = (v * PRIME) & BIT_MASK;
    uint32_t w = p >> 6, s = p & 63u;
    unsigned long long lo = bits[w];
    unsigned long long win;
    if (s <= 57u) win = lo >> s;
    else win = (lo >> s) | (bits[(w + 1u) & WORD_MASK] << (64u - s));
    return ((win & 0x7Full) == 0x7Full) ? 1 : 0;
}

__global__ __launch_bounds__(256) void query_kernelH(
    const int* __restrict__ vals, int n,
    const unsigned long long* __restrict__ bits,
    const uint32_t* __restrict__ H32, int* __restrict__ out)
{
    int t = blockIdx.x * 256 + threadIdx.x;
    int base = t * 8;
    if (base + 7 < n) {
        vint4 v0 = __builtin_nontemporal_load((const vint4*)(vals + base));
        vint4 v1 = __builtin_nontemporal_load((const vint4*)(vals + base + 4));
        uint32_t p[8], pass[8];
        #pragma unroll
        for (int j = 0; j < 4; ++j) {
            p[j]     = ((uint32_t)v0[j] * PRIME) & BIT_MASK;
            p[j + 4] = ((uint32_t)v1[j] * PRIME) & BIT_MASK;
        }
        #pragma unroll
        for (int j = 0; j < 8; ++j) {           // 8 independent L2-hit H probes
            uint32_t m = ((p[j] + 3u) & BIT_MASK) >> 2;
            pass[j] = (H32[m >> 5] >> (m & 31u)) & 1u;
        }
        unsigned long long lo[8], hi[8];
        uint32_t w[8], s[8];
        #pragma unroll
        for (int j = 0; j < 8; ++j) {           // masked fine gathers (~13% lanes), CACHED
            w[j] = p[j] >> 6; s[j] = p[j] & 63u;
            lo[j] = 0ull; hi[j] = 0ull;
            if (pass[j]) lo[j] = bits[w[j]];
        }
        #pragma unroll
        for (int j = 0; j < 8; ++j) {           // masked hi gathers (~1.1% lanes), CACHED
            if (pass[j] && s[j] > 57u)
                hi[j] = bits[(w[j] + 1u) & WORD_MASK];
        }
        vint4 r0, r1;
        #pragma unroll
        for (int j = 0; j < 8; ++j) {
            unsigned long long win = (lo[j] >> s[j]) | ((hi[j] << 1) << (63u - s[j]));
            int r = ((win & 0x7Full) == 0x7Full) ? 1 : 0;
            if (j < 4) r0[j] = r; else r1[j - 4] = r;
        }
        __builtin_nontemporal_store(r0, (vint4*)(out + base));
        __builtin_nontemporal_store(r1, (vint4*)(out + base + 4));
    } else {
        for (int j = base; j < n; ++j)
            out[j] = query_one_branchy((uint32_t)vals[j], bits);
    }
}

// ---------- no-H fallback query (ws too small for H) ----------
__global__ __launch_bounds__(256) void query_kernel8(
    const int* __restrict__ vals, int n,
    const unsigned long long* __restrict__ bits, int* __restrict__ out)
{
    int t = blockIdx.x * 256 + threadIdx.x;
    int base = t * 8;
    if (base + 7 < n) {
        vint4 v0 = __builtin_nontemporal_load((const vint4*)(vals + base));
        vint4 v1 = __builtin_nontemporal_load((const vint4*)(vals + base + 4));
        vint4 r0, r1;
        #pragma unroll
        for (int j = 0; j < 8; ++j) {
            uint32_t v = (uint32_t)(j < 4 ? v0[j] : v1[j - 4]);
            int r = query_one_branchy(v, bits);
            if (j < 4) r0[j] = r; else r1[j - 4] = r;
        }
        __builtin_nontemporal_store(r0, (vint4*)(out + base));
        __builtin_nontemporal_store(r1, (vint4*)(out + base + 4));
    } else {
        for (int j = base; j < n; ++j)
            out[j] = query_one_branchy((uint32_t)vals[j], bits);
    }
}

extern "C" void kernel_launch(void* const* d_in, const int* in_sizes, int n_in,
                              void* d_out, int out_size, void* d_ws, size_t ws_size,
                              hipStream_t stream) {
    const int* add_values   = (const int*)d_in[0];
    const int* query_values = (const int*)d_in[1];
    const int n_add   = in_sizes[0];   // 4,000,000
    const int n_query = in_sizes[1];   // 8,000,000
    int* out = (int*)d_out;

    uint8_t* ws = (uint8_t*)d_ws;
    unsigned long long* bits = (unsigned long long*)ws;
    unsigned long long* H    = (unsigned long long*)(ws + 16777216);

    // zero fine bitmap
    const int n2 = NUM_WORDS / 2;
    zero_bits_kernel<<<(n2 + 255) / 256, 256, 0, stream>>>((vull2*)bits, n2);

    // insert: fire-and-forget atomics (order-independent -> deterministic)
    const int threads4 = (n_add + 3) / 4;
    insert_atomic_kernel<<<(threads4 + 255) / 256, 256, 0, stream>>>(
        add_values, n_add, bits);

    const int threads = (n_query + 7) / 8;
    if (ws_size >= WS_REQUIRED) {
        // H summary build: coalesced, warms L3 with bits
        build_h_kernel<<<H_WORDS / 256, 256, 0, stream>>>(bits, H);
        query_kernelH<<<(threads + 255) / 256, 256, 0, stream>>>(
            query_values, n_query, bits, (const uint32_t*)H, out);
    } else {
        query_kernel8<<<(threads + 255) / 256, 256, 0, stream>>>(
            query_values, n_query, bits, out);
    }
}

// Round 2
// 245.850 us; speedup vs baseline: 1.3062x; 1.3062x over previous
//
#include <hip/hip_runtime.h>
#include <stdint.h>

// Bloom filter, 2^27 bits, 7 hashes = 7 CONSECUTIVE bits starting at
//   p = ((uint32)v * 2654435761u) & (2^27 - 1)   (wraps mod 2^27)
// Harness dtypes: integer inputs -> int32; bool output -> int32 (0/1).
//
// R10: insert = bucket scatter with GLOBAL chunk reservation.
//   R9 post-mortem: direct global atomicOr ran at the random-RMW ceiling
//   (WRITE_SIZE 136MB = 4.4M atomics x 32B memory-side transactions,
//   ~880 GB/s scattered). LDS aggregation is structurally required.
//   vs R8: since the bitmap is an OR-reduction, list order is irrelevant ->
//   blocks reserve contiguous chunks via one atomicAdd per (block,bucket)
//   instead of exact per-block segments. Kills the per-block 512-wide scan,
//   the transposed offset table, AND makes phase-B list reads dense ->
//   fully coalesced cooperative loads (R8 walked segments per-lane, serial).
// Query: cached gathers (R9 fix); bits written temporally in build so the
//   query gathers hit L3.

#define NUM_BITS_LOG2 27
#define NUM_BITS (1u << NUM_BITS_LOG2)
#define BIT_MASK (NUM_BITS - 1u)
#define NUM_WORDS (NUM_BITS >> 6)             // 2^21 u64 words = 16 MiB
#define WORD_MASK (NUM_WORDS - 1u)
#define PRIME 2654435761u
#define H_WORDS (NUM_WORDS >> 2)              // 2^19 u64 H-words = 4 MiB

#define NBUCKETS 512
#define BKT_SHIFT (NUM_BITS_LOG2 - 9)         // 18: region = 2^18 bits
#define REGION_WORDS (1u << (BKT_SHIFT - 6))  // 4096 u64 = 32 KiB
#define H_WORDS_PER_REGION (REGION_WORDS / 4) // 1024 u64 H-words per region
#define CAP 8688u                             // per-bucket list capacity (mean 7813 + 9.9 sigma)
#define BLOCKS_A 1024

typedef int vint4 __attribute__((ext_vector_type(4)));
typedef unsigned long long vull2 __attribute__((ext_vector_type(2)));

// ---------------- workspace layout (bytes) ----------------
// [0, 16777216)            bits   u64 x 2^21   (16 MiB)
// [16777216, 20971520)     H      u64 x 2^19   (4 MiB)
// [20971520, 38764544)     lists  u32 x 512*8688
// [38764544, 38766592)     gcnt   u32 x 512
#define WS_H_ONLY 20971520ull
#define WS_FULL   38766592ull

// ---------- tiny init: zero the global bucket cursors ----------
__global__ __launch_bounds__(512) void init_gcnt_kernel(uint32_t* __restrict__ gcnt) {
    gcnt[threadIdx.x] = 0u;
}

// ---------- phase A: count -> reserve -> scatter (no exact global scan) ----------
__global__ __launch_bounds__(256) void scatter_kernel(
    const int* __restrict__ vals, int n,
    uint32_t* __restrict__ lists, uint32_t* __restrict__ gcnt)
{
    __shared__ uint32_t cnt[NBUCKETS];
    __shared__ uint32_t cur[NBUCKETS];
    const int tid = threadIdx.x;
    const int g0 = blockIdx.x * 256 + tid;
    const int gstride = BLOCKS_A * 256;
    for (int i = tid; i < NBUCKETS; i += 256) cnt[i] = 0u;
    __syncthreads();

    const int n4 = n >> 2;
    // ---- pass 1: local histogram (traversal identical to pass 2) ----
    for (int g = g0; g < n4; g += gstride) {
        vint4 v = __builtin_nontemporal_load((const vint4*)vals + g);
        #pragma unroll
        for (int j = 0; j < 4; ++j) {
            uint32_t p = ((uint32_t)v[j] * PRIME) & BIT_MASK;
            uint32_t b1 = p >> BKT_SHIFT;
            atomicAdd(&cnt[b1], 1u);
            uint32_t b2 = ((p + 6u) & BIT_MASK) >> BKT_SHIFT;
            if (b2 != b1) atomicAdd(&cnt[b2], 1u);   // region straddle: ~100 total
        }
    }
    for (int i = (n4 << 2) + g0; i < n; i += gstride) {
        uint32_t p = ((uint32_t)vals[i] * PRIME) & BIT_MASK;
        uint32_t b1 = p >> BKT_SHIFT;
        atomicAdd(&cnt[b1], 1u);
        uint32_t b2 = ((p + 6u) & BIT_MASK) >> BKT_SHIFT;
        if (b2 != b1) atomicAdd(&cnt[b2], 1u);
    }
    __syncthreads();

    // ---- reserve a contiguous chunk per bucket (order irrelevant: OR-reduction) ----
    for (int i = tid; i < NBUCKETS; i += 256) {
        uint32_t c = cnt[i];
        cur[i] = c ? atomicAdd(&gcnt[i], c) : 0u;   // relative base within bucket
    }
    __syncthreads();

    // ---- pass 2: scatter into reserved chunks ----
    for (int g = g0; g < n4; g += gstride) {
        vint4 v = __builtin_nontemporal_load((const vint4*)vals + g);
        #pragma unroll
        for (int j = 0; j < 4; ++j) {
            uint32_t p = ((uint32_t)v[j] * PRIME) & BIT_MASK;
            uint32_t b1 = p >> BKT_SHIFT;
            uint32_t s = atomicAdd(&cur[b1], 1u);
            if (s < CAP) lists[b1 * CAP + s] = p;   // clamp: statistically unreachable
            uint32_t b2 = ((p + 6u) & BIT_MASK) >> BKT_SHIFT;
            if (b2 != b1) {
                uint32_t s2 = atomicAdd(&cur[b2], 1u);
                if (s2 < CAP) lists[b2 * CAP + s2] = p;
            }
        }
    }
    for (int i = (n4 << 2) + g0; i < n; i += gstride) {
        uint32_t p = ((uint32_t)vals[i] * PRIME) & BIT_MASK;
        uint32_t b1 = p >> BKT_SHIFT;
        uint32_t s = atomicAdd(&cur[b1], 1u);
        if (s < CAP) lists[b1 * CAP + s] = p;
        uint32_t b2 = ((p + 6u) & BIT_MASK) >> BKT_SHIFT;
        if (b2 != b1) {
            uint32_t s2 = atomicAdd(&cur[b2], 1u);
            if (s2 < CAP) lists[b2 * CAP + s2] = p;
        }
    }
}

// ---------- phase B: build region bitmap in LDS, emit bits + H ----------
__device__ __forceinline__ void set_window(unsigned long long* bm, uint32_t p, uint32_t b) {
    int d = (int)((p - (b << BKT_SHIFT)) & BIT_MASK);
    if (d >= (1 << 26)) d -= (1 << 27);                 // dup from prev region / wrap
    if (d < -6 || d >= (1 << BKT_SHIFT)) return;        // safety guard
    if (d < 0) {
        atomicOr(&bm[0], 0x7Full >> (uint32_t)(-d));
    } else {
        uint32_t w = (uint32_t)d >> 6, s = (uint32_t)d & 63u;
        atomicOr(&bm[w], 0x7Full << s);
        if (s > 57u) atomicOr(&bm[w + 1], 0x7Full >> (64u - s));  // slack word absorbs
    }
}

// 16 nibble-AND bits of one u64 fine word, compacted to low 16 bits
__device__ __forceinline__ unsigned long long nib16(unsigned long long a) {
    unsigned long long t = a & (a >> 1);
    unsigned long long u = t & (t >> 2);                // bit 4k = AND of bits 4k..4k+3
    u &= 0x1111111111111111ull;
    u |= u >> 3;  u &= 0x0303030303030303ull;
    u |= u >> 6;  u &= 0x000F000F000F000Full;
    u |= u >> 12; u &= 0x000000FF000000FFull;
    u |= u >> 24; return u & 0xFFFFull;
}

__global__ __launch_bounds__(256) void build_bitmap_kernel(
    const uint32_t* __restrict__ lists, const uint32_t* __restrict__ gcnt,
    unsigned long long* __restrict__ bits, unsigned long long* __restrict__ H)
{
    __shared__ unsigned long long bm[REGION_WORDS + 1];
    const uint32_t b = blockIdx.x, tid = threadIdx.x;
    for (uint32_t i = tid; i < REGION_WORDS + 1; i += 256) bm[i] = 0ull;
    __syncthreads();

    // dense bucket list -> fully coalesced cooperative read
    const uint32_t m = min(gcnt[b], CAP);
    const uint32_t base = b * CAP;
    for (uint32_t i = tid; i < m; i += 256) set_window(bm, lists[base + i], b);
    __syncthreads();

    const uint32_t out_base = b * REGION_WORDS;
    for (uint32_t i = tid; i < REGION_WORDS / 2; i += 256) {
        vull2 w; w[0] = bm[i * 2]; w[1] = bm[i * 2 + 1];
        *((vull2*)(bits + out_base) + i) = w;           // temporal: warm L3 for query
    }
    const uint32_t h_base = b * H_WORDS_PER_REGION;
    for (uint32_t i = tid; i < H_WORDS_PER_REGION; i += 256) {
        unsigned long long hw = nib16(bm[i * 4])
                              | (nib16(bm[i * 4 + 1]) << 16)
                              | (nib16(bm[i * 4 + 2]) << 32)
                              | (nib16(bm[i * 4 + 3]) << 48);
        H[h_base + i] = hw;                 // temporal: H wants to live in L2
    }
}

// ---------- query: H pre-filter (L2-resident), fine bitmap only on pass ----------
__device__ __forceinline__ int query_one_branchy(uint32_t v,
                                                 const unsigned long long* __restrict__ bits) {
    uint32_t p = (v * PRIME) & BIT_MASK;
    uint32_t w = p >> 6, s = p & 63u;
    unsigned long long lo = bits[w];
    unsigned long long win;
    if (s <= 57u) win = lo >> s;
    else win = (lo >> s) | (bits[(w + 1u) & WORD_MASK] << (64u - s));
    return ((win & 0x7Full) == 0x7Full) ? 1 : 0;
}

__global__ __launch_bounds__(256) void query_kernelH(
    const int* __restrict__ vals, int n,
    const unsigned long long* __restrict__ bits,
    const uint32_t* __restrict__ H32, int* __restrict__ out)
{
    int t = blockIdx.x * 256 + threadIdx.x;
    int base = t * 8;
    if (base + 7 < n) {
        vint4 v0 = __builtin_nontemporal_load((const vint4*)(vals + base));
        vint4 v1 = __builtin_nontemporal_load((const vint4*)(vals + base + 4));
        uint32_t p[8], pass[8];
        #pragma unroll
        for (int j = 0; j < 4; ++j) {
            p[j]     = ((uint32_t)v0[j] * PRIME) & BIT_MASK;
            p[j + 4] = ((uint32_t)v1[j] * PRIME) & BIT_MASK;
        }
        #pragma unroll
        for (int j = 0; j < 8; ++j) {           // 8 independent L2-hit H probes
            uint32_t m = ((p[j] + 3u) & BIT_MASK) >> 2;
            pass[j] = (H32[m >> 5] >> (m & 31u)) & 1u;
        }
        unsigned long long lo[8], hi[8];
        uint32_t w[8], s[8];
        #pragma unroll
        for (int j = 0; j < 8; ++j) {           // masked fine gathers (~13% lanes), CACHED
            w[j] = p[j] >> 6; s[j] = p[j] & 63u;
            lo[j] = 0ull; hi[j] = 0ull;
            if (pass[j]) lo[j] = bits[w[j]];
        }
        #pragma unroll
        for (int j = 0; j < 8; ++j) {           // masked hi gathers (~1.1% lanes), CACHED
            if (pass[j] && s[j] > 57u)
                hi[j] = bits[(w[j] + 1u) & WORD_MASK];
        }
        vint4 r0, r1;
        #pragma unroll
        for (int j = 0; j < 8; ++j) {
            unsigned long long win = (lo[j] >> s[j]) | ((hi[j] << 1) << (63u - s[j]));
            int r = ((win & 0x7Full) == 0x7Full) ? 1 : 0;
            if (j < 4) r0[j] = r; else r1[j - 4] = r;
        }
        __builtin_nontemporal_store(r0, (vint4*)(out + base));
        __builtin_nontemporal_store(r1, (vint4*)(out + base + 4));
    } else {
        for (int j = base; j < n; ++j)
            out[j] = query_one_branchy((uint32_t)vals[j], bits);
    }
}

// ---------- fallback path (small ws): global-atomic insert + plain query ----------
__global__ __launch_bounds__(256) void zero_bits_kernel(vull2* __restrict__ bits, int n2) {
    int i = blockIdx.x * 256 + threadIdx.x;
    if (i < n2) { vull2 z = {0ull, 0ull}; __builtin_nontemporal_store(z, &bits[i]); }
}

__device__ __forceinline__ void insert_one_atomic(uint32_t v,
                                                  unsigned long long* __restrict__ bits) {
    uint32_t p = (v * PRIME) & BIT_MASK;
    uint32_t w = p >> 6, s = p & 63u;
    atomicOr(bits + w, 0x7Full << s);
    if (s > 57u) atomicOr(bits + ((w + 1u) & WORD_MASK), 0x7Full >> (64u - s));
}

__global__ __launch_bounds__(256) void insert_atomic_kernel(const int* __restrict__ vals, int n,
                                                            unsigned long long* __restrict__ bits) {
    int t = blockIdx.x * 256 + threadIdx.x;
    int base = t * 4;
    if (base + 3 < n) {
        vint4 v = __builtin_nontemporal_load((const vint4*)vals + t);
        insert_one_atomic((uint32_t)v.x, bits);
        insert_one_atomic((uint32_t)v.y, bits);
        insert_one_atomic((uint32_t)v.z, bits);
        insert_one_atomic((uint32_t)v.w, bits);
    } else {
        for (int j = base; j < n; ++j) insert_one_atomic((uint32_t)vals[j], bits);
    }
}

__global__ __launch_bounds__(256) void build_h_kernel(
    const unsigned long long* __restrict__ bits, unsigned long long* __restrict__ H)
{
    uint32_t i = blockIdx.x * 256 + threadIdx.x;        // [0, 2^19), grid exact
    const vull2* b2 = (const vull2*)bits + (size_t)i * 2;
    vull2 a = b2[0];
    vull2 b = b2[1];
    unsigned long long hw = nib16(a[0])
                          | (nib16(a[1]) << 16)
                          | (nib16(b[0]) << 32)
                          | (nib16(b[1]) << 48);
    H[i] = hw;
}

__global__ __launch_bounds__(256) void query_kernel8(
    const int* __restrict__ vals, int n,
    const unsigned long long* __restrict__ bits, int* __restrict__ out)
{
    int t = blockIdx.x * 256 + threadIdx.x;
    int base = t * 8;
    if (base + 7 < n) {
        vint4 v0 = __builtin_nontemporal_load((const vint4*)(vals + base));
        vint4 v1 = __builtin_nontemporal_load((const vint4*)(vals + base + 4));
        vint4 r0, r1;
        #pragma unroll
        for (int j = 0; j < 8; ++j) {
            uint32_t v = (uint32_t)(j < 4 ? v0[j] : v1[j - 4]);
            int r = query_one_branchy(v, bits);
            if (j < 4) r0[j] = r; else r1[j - 4] = r;
        }
        __builtin_nontemporal_store(r0, (vint4*)(out + base));
        __builtin_nontemporal_store(r1, (vint4*)(out + base + 4));
    } else {
        for (int j = base; j < n; ++j)
            out[j] = query_one_branchy((uint32_t)vals[j], bits);
    }
}

extern "C" void kernel_launch(void* const* d_in, const int* in_sizes, int n_in,
                              void* d_out, int out_size, void* d_ws, size_t ws_size,
                              hipStream_t stream) {
    const int* add_values   = (const int*)d_in[0];
    const int* query_values = (const int*)d_in[1];
    const int n_add   = in_sizes[0];   // 4,000,000
    const int n_query = in_sizes[1];   // 8,000,000
    int* out = (int*)d_out;

    uint8_t* ws = (uint8_t*)d_ws;
    unsigned long long* bits = (unsigned long long*)ws;
    unsigned long long* H    = (unsigned long long*)(ws + 16777216);
    uint32_t* lists = (uint32_t*)(ws + 20971520);
    uint32_t* gcnt  = (uint32_t*)(ws + 38764544);

    const int threads = (n_query + 7) / 8;

    if (ws_size >= WS_FULL) {
        init_gcnt_kernel<<<1, 512, 0, stream>>>(gcnt);
        scatter_kernel<<<BLOCKS_A, 256, 0, stream>>>(add_values, n_add, lists, gcnt);
        build_bitmap_kernel<<<NBUCKETS, 256, 0, stream>>>(lists, gcnt, bits, H);
        query_kernelH<<<(threads + 255) / 256, 256, 0, stream>>>(
            query_values, n_query, bits, (const uint32_t*)H, out);
    } else if (ws_size >= WS_H_ONLY) {
        const int n2 = NUM_WORDS / 2;
        zero_bits_kernel<<<(n2 + 255) / 256, 256, 0, stream>>>((vull2*)bits, n2);
        const int threads4 = (n_add + 3) / 4;
        insert_atomic_kernel<<<(threads4 + 255) / 256, 256, 0, stream>>>(
            add_values, n_add, bits);
        build_h_kernel<<<H_WORDS / 256, 256, 0, stream>>>(bits, H);
        query_kernelH<<<(threads + 255) / 256, 256, 0, stream>>>(
            query_values, n_query, bits, (const uint32_t*)H, out);
    } else {
        const int n2 = NUM_WORDS / 2;
        zero_bits_kernel<<<(n2 + 255) / 256, 256, 0, stream>>>((vull2*)bits, n2);
        const int threads4 = (n_add + 3) / 4;
        insert_atomic_kernel<<<(threads4 + 255) / 256, 256, 0, stream>>>(
            add_values, n_add, bits);
        query_kernel8<<<(threads + 255) / 256, 256, 0, stream>>>(
            query_values, n_query, bits, out);
    }
}

// Round 3
// 186.421 us; speedup vs baseline: 1.7225x; 1.3188x over previous
//
#include <hip/hip_runtime.h>
#include <stdint.h>

// Bloom filter, 2^27 bits, 7 hashes = 7 CONSECUTIVE bits starting at
//   p = ((uint32)v * 2654435761u) & (2^27 - 1)   (wraps mod 2^27)
// Harness dtypes: integer inputs -> int32; bool output -> int32 (0/1).
//
// R11: scatter now counting-sorts each 8192-value chunk in LDS and flushes
// bucket-grouped runs -> coalesced list writes.
//   R10 post-mortem: scatter was bound by scattered 4B list writes:
//   WRITE_SIZE 87.5MB vs 16MB payload (5x amplification; each entry its own
//   32B memory-side transaction), ~75us at the ~1TB/s random-write rate.
//   Sorted flush: slot i -> dst gdelta[p>>18] + i, runs of ~16 entries ->
//   a wave touches ~5 line segments instead of 64 lines.
//   Straddle dups (~92 total, bucket not derivable from p) written directly.
// Phase B / query / fallbacks unchanged (clean attribution).

#define NUM_BITS_LOG2 27
#define NUM_BITS (1u << NUM_BITS_LOG2)
#define BIT_MASK (NUM_BITS - 1u)
#define NUM_WORDS (NUM_BITS >> 6)             // 2^21 u64 words = 16 MiB
#define WORD_MASK (NUM_WORDS - 1u)
#define PRIME 2654435761u
#define H_WORDS (NUM_WORDS >> 2)              // 2^19 u64 H-words = 4 MiB

#define NBUCKETS 512
#define BKT_SHIFT (NUM_BITS_LOG2 - 9)         // 18: region = 2^18 bits
#define REGION_WORDS (1u << (BKT_SHIFT - 6))  // 4096 u64 = 32 KiB
#define H_WORDS_PER_REGION (REGION_WORDS / 4) // 1024 u64 H-words per region
#define CAP 8688u                             // per-bucket list capacity (mean 7813 + 9.9 sigma)
#define CHUNK 8192u                           // values per sorted chunk (32 KiB LDS)
#define BLOCKS_A 512

typedef int vint4 __attribute__((ext_vector_type(4)));
typedef unsigned long long vull2 __attribute__((ext_vector_type(2)));

// ---------------- workspace layout (bytes) ----------------
// [0, 16777216)            bits   u64 x 2^21   (16 MiB)
// [16777216, 20971520)     H      u64 x 2^19   (4 MiB)
// [20971520, 38764544)     lists  u32 x 512*8688
// [38764544, 38766592)     gcnt   u32 x 512
#define WS_H_ONLY 20971520ull
#define WS_FULL   38766592ull

// ---------- tiny init: zero the global bucket cursors ----------
__global__ __launch_bounds__(512) void init_gcnt_kernel(uint32_t* __restrict__ gcnt) {
    gcnt[threadIdx.x] = 0u;
}

// ---------- phase A: per-chunk LDS counting sort -> coalesced list flush ----------
__global__ __launch_bounds__(256) void scatter_kernel(
    const int* __restrict__ vals, int n,
    uint32_t* __restrict__ lists, uint32_t* __restrict__ gcnt)
{
    __shared__ uint32_t hist[NBUCKETS];
    __shared__ uint32_t sc[NBUCKETS];      // inclusive scan
    __shared__ uint32_t cur[NBUCKETS];     // local slot cursors
    __shared__ uint32_t gdelta[NBUCKETS];  // slot i -> global list index (u32 wrap ok)
    __shared__ uint32_t sortbuf[CHUNK];
    const uint32_t tid = threadIdx.x;
    const uint32_t un = (uint32_t)n;
    const uint32_t nchunks = (un + CHUNK - 1u) / CHUNK;

    for (uint32_t c = blockIdx.x; c < nchunks; c += gridDim.x) {
        const uint32_t base = c * CHUNK;
        const bool full = (base + CHUNK <= un);

        hist[tid] = 0u; hist[tid + 256] = 0u;
        __syncthreads();

        // ---- pass 1: histogram (+ direct write of rare straddle dups) ----
        vint4 vv[8];
        if (full) {
            const vint4* src = (const vint4*)(vals + base);
            #pragma unroll
            for (int k = 0; k < 8; ++k) vv[k] = src[(uint32_t)k * 256u + tid];
            #pragma unroll
            for (int k = 0; k < 8; ++k) {
                #pragma unroll
                for (int j = 0; j < 4; ++j) {
                    uint32_t p = ((uint32_t)vv[k][j] * PRIME) & BIT_MASK;
                    uint32_t b1 = p >> BKT_SHIFT;
                    atomicAdd(&hist[b1], 1u);
                    uint32_t b2 = ((p + 6u) & BIT_MASK) >> BKT_SHIFT;
                    if (b2 != b1) {                     // ~92 total in whole input
                        uint32_t s2 = atomicAdd(&gcnt[b2], 1u);
                        if (s2 < CAP) lists[b2 * CAP + s2] = p;
                    }
                }
            }
        } else {
            #pragma unroll
            for (int k = 0; k < 32; ++k) {
                uint32_t idx = base + (uint32_t)k * 256u + tid;
                if (idx < un) {
                    uint32_t p = ((uint32_t)vals[idx] * PRIME) & BIT_MASK;
                    uint32_t b1 = p >> BKT_SHIFT;
                    atomicAdd(&hist[b1], 1u);
                    uint32_t b2 = ((p + 6u) & BIT_MASK) >> BKT_SHIFT;
                    if (b2 != b1) {
                        uint32_t s2 = atomicAdd(&gcnt[b2], 1u);
                        if (s2 < CAP) lists[b2 * CAP + s2] = p;
                    }
                }
            }
        }
        __syncthreads();

        // ---- inclusive Hillis-Steele scan over 512 bins (each thread owns 2) ----
        sc[tid] = hist[tid]; sc[tid + 256] = hist[tid + 256];
        __syncthreads();
        for (uint32_t d = 1; d < NBUCKETS; d <<= 1) {
            uint32_t v0 = (tid >= d) ? sc[tid - d] : 0u;
            uint32_t v1 = (tid + 256u >= d) ? sc[tid + 256u - d] : 0u;
            __syncthreads();
            sc[tid] += v0; sc[tid + 256] += v1;
            __syncthreads();
        }

        // ---- reserve global chunks; build slot->global mapping ----
        #pragma unroll
        for (int q = 0; q < 2; ++q) {
            uint32_t i = tid + (uint32_t)q * 256u;
            uint32_t lb = i ? sc[i - 1] : 0u;
            uint32_t cc = hist[i];
            uint32_t go = cc ? atomicAdd(&gcnt[i], cc) : 0u;
            cur[i] = lb;
            gdelta[i] = i * CAP + go - lb;              // u32 wraparound exact
        }
        __syncthreads();

        // ---- pass 2: counting-sort p values into LDS ----
        if (full) {
            #pragma unroll
            for (int k = 0; k < 8; ++k) {
                #pragma unroll
                for (int j = 0; j < 4; ++j) {
                    uint32_t p = ((uint32_t)vv[k][j] * PRIME) & BIT_MASK;
                    uint32_t b1 = p >> BKT_SHIFT;
                    uint32_t s = atomicAdd(&cur[b1], 1u);
                    sortbuf[s] = p;
                }
            }
        } else {
            #pragma unroll
            for (int k = 0; k < 32; ++k) {
                uint32_t idx = base + (uint32_t)k * 256u + tid;
                if (idx < un) {
                    uint32_t p = ((uint32_t)vals[idx] * PRIME) & BIT_MASK;
                    uint32_t b1 = p >> BKT_SHIFT;
                    uint32_t s = atomicAdd(&cur[b1], 1u);
                    sortbuf[s] = p;
                }
            }
        }
        __syncthreads();

        // ---- flush: slots grouped by ascending bucket -> coalesced run writes ----
        const uint32_t total = sc[NBUCKETS - 1];
        for (uint32_t i = tid; i < total; i += 256u) {
            uint32_t p = sortbuf[i];
            uint32_t b = p >> BKT_SHIFT;
            uint32_t dst = gdelta[b] + i;
            if (dst - b * CAP < CAP) lists[dst] = p;    // clamp: statistically unreachable
        }
        __syncthreads();                                // protect LDS reuse next iter
    }
}

// ---------- phase B: build region bitmap in LDS, emit bits + H ----------
__device__ __forceinline__ void set_window(unsigned long long* bm, uint32_t p, uint32_t b) {
    int d = (int)((p - (b << BKT_SHIFT)) & BIT_MASK);
    if (d >= (1 << 26)) d -= (1 << 27);                 // dup from prev region / wrap
    if (d < -6 || d >= (1 << BKT_SHIFT)) return;        // safety guard
    if (d < 0) {
        atomicOr(&bm[0], 0x7Full >> (uint32_t)(-d));
    } else {
        uint32_t w = (uint32_t)d >> 6, s = (uint32_t)d & 63u;
        atomicOr(&bm[w], 0x7Full << s);
        if (s > 57u) atomicOr(&bm[w + 1], 0x7Full >> (64u - s));  // slack word absorbs
    }
}

// 16 nibble-AND bits of one u64 fine word, compacted to low 16 bits
__device__ __forceinline__ unsigned long long nib16(unsigned long long a) {
    unsigned long long t = a & (a >> 1);
    unsigned long long u = t & (t >> 2);                // bit 4k = AND of bits 4k..4k+3
    u &= 0x1111111111111111ull;
    u |= u >> 3;  u &= 0x0303030303030303ull;
    u |= u >> 6;  u &= 0x000F000F000F000Full;
    u |= u >> 12; u &= 0x000000FF000000FFull;
    u |= u >> 24; return u & 0xFFFFull;
}

__global__ __launch_bounds__(256) void build_bitmap_kernel(
    const uint32_t* __restrict__ lists, const uint32_t* __restrict__ gcnt,
    unsigned long long* __restrict__ bits, unsigned long long* __restrict__ H)
{
    __shared__ unsigned long long bm[REGION_WORDS + 1];
    const uint32_t b = blockIdx.x, tid = threadIdx.x;
    for (uint32_t i = tid; i < REGION_WORDS + 1; i += 256) bm[i] = 0ull;
    __syncthreads();

    // dense bucket list -> fully coalesced cooperative read
    const uint32_t m = min(gcnt[b], CAP);
    const uint32_t base = b * CAP;
    for (uint32_t i = tid; i < m; i += 256) set_window(bm, lists[base + i], b);
    __syncthreads();

    const uint32_t out_base = b * REGION_WORDS;
    for (uint32_t i = tid; i < REGION_WORDS / 2; i += 256) {
        vull2 w; w[0] = bm[i * 2]; w[1] = bm[i * 2 + 1];
        *((vull2*)(bits + out_base) + i) = w;           // temporal: warm L3 for query
    }
    const uint32_t h_base = b * H_WORDS_PER_REGION;
    for (uint32_t i = tid; i < H_WORDS_PER_REGION; i += 256) {
        unsigned long long hw = nib16(bm[i * 4])
                              | (nib16(bm[i * 4 + 1]) << 16)
                              | (nib16(bm[i * 4 + 2]) << 32)
                              | (nib16(bm[i * 4 + 3]) << 48);
        H[h_base + i] = hw;                 // temporal: H wants to live in L2
    }
}

// ---------- query: H pre-filter (L2-resident), fine bitmap only on pass ----------
__device__ __forceinline__ int query_one_branchy(uint32_t v,
                                                 const unsigned long long* __restrict__ bits) {
    uint32_t p = (v * PRIME) & BIT_MASK;
    uint32_t w = p >> 6, s = p & 63u;
    unsigned long long lo = bits[w];
    unsigned long long win;
    if (s <= 57u) win = lo >> s;
    else win = (lo >> s) | (bits[(w + 1u) & WORD_MASK] << (64u - s));
    return ((win & 0x7Full) == 0x7Full) ? 1 : 0;
}

__global__ __launch_bounds__(256) void query_kernelH(
    const int* __restrict__ vals, int n,
    const unsigned long long* __restrict__ bits,
    const uint32_t* __restrict__ H32, int* __restrict__ out)
{
    int t = blockIdx.x * 256 + threadIdx.x;
    int base = t * 8;
    if (base + 7 < n) {
        vint4 v0 = __builtin_nontemporal_load((const vint4*)(vals + base));
        vint4 v1 = __builtin_nontemporal_load((const vint4*)(vals + base + 4));
        uint32_t p[8], pass[8];
        #pragma unroll
        for (int j = 0; j < 4; ++j) {
            p[j]     = ((uint32_t)v0[j] * PRIME) & BIT_MASK;
            p[j + 4] = ((uint32_t)v1[j] * PRIME) & BIT_MASK;
        }
        #pragma unroll
        for (int j = 0; j < 8; ++j) {           // 8 independent L2-hit H probes
            uint32_t m = ((p[j] + 3u) & BIT_MASK) >> 2;
            pass[j] = (H32[m >> 5] >> (m & 31u)) & 1u;
        }
        unsigned long long lo[8], hi[8];
        uint32_t w[8], s[8];
        #pragma unroll
        for (int j = 0; j < 8; ++j) {           // masked fine gathers (~13% lanes), CACHED
            w[j] = p[j] >> 6; s[j] = p[j] & 63u;
            lo[j] = 0ull; hi[j] = 0ull;
            if (pass[j]) lo[j] = bits[w[j]];
        }
        #pragma unroll
        for (int j = 0; j < 8; ++j) {           // masked hi gathers (~1.1% lanes), CACHED
            if (pass[j] && s[j] > 57u)
                hi[j] = bits[(w[j] + 1u) & WORD_MASK];
        }
        vint4 r0, r1;
        #pragma unroll
        for (int j = 0; j < 8; ++j) {
            unsigned long long win = (lo[j] >> s[j]) | ((hi[j] << 1) << (63u - s[j]));
            int r = ((win & 0x7Full) == 0x7Full) ? 1 : 0;
            if (j < 4) r0[j] = r; else r1[j - 4] = r;
        }
        __builtin_nontemporal_store(r0, (vint4*)(out + base));
        __builtin_nontemporal_store(r1, (vint4*)(out + base + 4));
    } else {
        for (int j = base; j < n; ++j)
            out[j] = query_one_branchy((uint32_t)vals[j], bits);
    }
}

// ---------- fallback path (small ws): global-atomic insert + plain query ----------
__global__ __launch_bounds__(256) void zero_bits_kernel(vull2* __restrict__ bits, int n2) {
    int i = blockIdx.x * 256 + threadIdx.x;
    if (i < n2) { vull2 z = {0ull, 0ull}; __builtin_nontemporal_store(z, &bits[i]); }
}

__device__ __forceinline__ void insert_one_atomic(uint32_t v,
                                                  unsigned long long* __restrict__ bits) {
    uint32_t p = (v * PRIME) & BIT_MASK;
    uint32_t w = p >> 6, s = p & 63u;
    atomicOr(bits + w, 0x7Full << s);
    if (s > 57u) atomicOr(bits + ((w + 1u) & WORD_MASK), 0x7Full >> (64u - s));
}

__global__ __launch_bounds__(256) void insert_atomic_kernel(const int* __restrict__ vals, int n,
                                                            unsigned long long* __restrict__ bits) {
    int t = blockIdx.x * 256 + threadIdx.x;
    int base = t * 4;
    if (base + 3 < n) {
        vint4 v = __builtin_nontemporal_load((const vint4*)vals + t);
        insert_one_atomic((uint32_t)v.x, bits);
        insert_one_atomic((uint32_t)v.y, bits);
        insert_one_atomic((uint32_t)v.z, bits);
        insert_one_atomic((uint32_t)v.w, bits);
    } else {
        for (int j = base; j < n; ++j) insert_one_atomic((uint32_t)vals[j], bits);
    }
}

__global__ __launch_bounds__(256) void build_h_kernel(
    const unsigned long long* __restrict__ bits, unsigned long long* __restrict__ H)
{
    uint32_t i = blockIdx.x * 256 + threadIdx.x;        // [0, 2^19), grid exact
    const vull2* b2 = (const vull2*)bits + (size_t)i * 2;
    vull2 a = b2[0];
    vull2 b = b2[1];
    unsigned long long hw = nib16(a[0])
                          | (nib16(a[1]) << 16)
                          | (nib16(b[0]) << 32)
                          | (nib16(b[1]) << 48);
    H[i] = hw;
}

__global__ __launch_bounds__(256) void query_kernel8(
    const int* __restrict__ vals, int n,
    const unsigned long long* __restrict__ bits, int* __restrict__ out)
{
    int t = blockIdx.x * 256 + threadIdx.x;
    int base = t * 8;
    if (base + 7 < n) {
        vint4 v0 = __builtin_nontemporal_load((const vint4*)(vals + base));
        vint4 v1 = __builtin_nontemporal_load((const vint4*)(vals + base + 4));
        vint4 r0, r1;
        #pragma unroll
        for (int j = 0; j < 8; ++j) {
            uint32_t v = (uint32_t)(j < 4 ? v0[j] : v1[j - 4]);
            int r = query_one_branchy(v, bits);
            if (j < 4) r0[j] = r; else r1[j - 4] = r;
        }
        __builtin_nontemporal_store(r0, (vint4*)(out + base));
        __builtin_nontemporal_store(r1, (vint4*)(out + base + 4));
    } else {
        for (int j = base; j < n; ++j)
            out[j] = query_one_branchy((uint32_t)vals[j], bits);
    }
}

extern "C" void kernel_launch(void* const* d_in, const int* in_sizes, int n_in,
                              void* d_out, int out_size, void* d_ws, size_t ws_size,
                              hipStream_t stream) {
    const int* add_values   = (const int*)d_in[0];
    const int* query_values = (const int*)d_in[1];
    const int n_add   = in_sizes[0];   // 4,000,000
    const int n_query = in_sizes[1];   // 8,000,000
    int* out = (int*)d_out;

    uint8_t* ws = (uint8_t*)d_ws;
    unsigned long long* bits = (unsigned long long*)ws;
    unsigned long long* H    = (unsigned long long*)(ws + 16777216);
    uint32_t* lists = (uint32_t*)(ws + 20971520);
    uint32_t* gcnt  = (uint32_t*)(ws + 38764544);

    const int threads = (n_query + 7) / 8;

    if (ws_size >= WS_FULL) {
        init_gcnt_kernel<<<1, 512, 0, stream>>>(gcnt);
        scatter_kernel<<<BLOCKS_A, 256, 0, stream>>>(add_values, n_add, lists, gcnt);
        build_bitmap_kernel<<<NBUCKETS, 256, 0, stream>>>(lists, gcnt, bits, H);
        query_kernelH<<<(threads + 255) / 256, 256, 0, stream>>>(
            query_values, n_query, bits, (const uint32_t*)H, out);
    } else if (ws_size >= WS_H_ONLY) {
        const int n2 = NUM_WORDS / 2;
        zero_bits_kernel<<<(n2 + 255) / 256, 256, 0, stream>>>((vull2*)bits, n2);
        const int threads4 = (n_add + 3) / 4;
        insert_atomic_kernel<<<(threads4 + 255) / 256, 256, 0, stream>>>(
            add_values, n_add, bits);
        build_h_kernel<<<H_WORDS / 256, 256, 0, stream>>>(bits, H);
        query_kernelH<<<(threads + 255) / 256, 256, 0, stream>>>(
            query_values, n_query, bits, (const uint32_t*)H, out);
    } else {
        const int n2 = NUM_WORDS / 2;
        zero_bits_kernel<<<(n2 + 255) / 256, 256, 0, stream>>>((vull2*)bits, n2);
        const int threads4 = (n_add + 3) / 4;
        insert_atomic_kernel<<<(threads4 + 255) / 256, 256, 0, stream>>>(
            add_values, n_add, bits);
        query_kernel8<<<(threads + 255) / 256, 256, 0, stream>>>(
            query_values, n_query, bits, out);
    }
}